// Round 10
// baseline (90.950 us; speedup 1.0000x reference)
//
#include <hip/hip_runtime.h>

typedef unsigned long long u64;
typedef unsigned int u32;

#define N1 4096
#define N2 2048
#define NT 6144
#define CAP 4096
#define MCAP 4096
#define IMG 1280.0f
#define MATCH_IOU_T 0.8f
#define NMS_IOU_T 0.95f

// IoU with exact op-order mirroring of the reference (no FMA contraction).
__device__ __forceinline__ float iou_f(const float* a, const float* b) {
    float x1 = fmaxf(a[0], b[0]);
    float y1 = fmaxf(a[1], b[1]);
    float x2 = fminf(a[2], b[2]);
    float y2 = fminf(a[3], b[3]);
    float dx = fmaxf(__fsub_rn(x2, x1), 0.0f);
    float dy = fmaxf(__fsub_rn(y2, y1), 0.0f);
    float inter = __fmul_rn(dx, dy);
    float a1 = __fmul_rn(__fsub_rn(a[2], a[0]), __fsub_rn(a[3], a[1]));
    float a2 = __fmul_rn(__fsub_rn(b[2], b[0]), __fsub_rn(b[3], b[1]));
    float den = __fsub_rn(__fadd_rn(a1, a2), inter);
    return __fdiv_rn(inter, den);
}

// K0: normalize frcnn boxes, weight scores, zero both pair counters.
__global__ void k0_prep(const float* fb, const float* fs, float* b2n, float* s2w,
                        int* pcount, int* mpcount) {
    int t = blockIdx.x * blockDim.x + threadIdx.x;
    if (t < N2 * 4) b2n[t] = __fdiv_rn(fb[t], IMG);
    if (t < N2)     s2w[t] = __fmul_rn(fs[t], 0.5f);
    if (t == 0)     { *pcount = 0; *mpcount = 0; }
}

// K1: 4 yolo rows per block; emit ALL candidate pairs (same label, unmasked
// IoU >= 0.8) with exact IoU (masking only removes js, so any merge winner is
// in this set). Threads 0..3 write the default (unmerged) mbox/mscore.
__global__ void __launch_bounds__(256) k1_pairs(const float* yb, const float* ys,
                                                const int* yl, const int* fl,
                                                const float* b2n, float* mbox,
                                                float* mscore, int* mpcount,
                                                u64* mpk, float* mpi) {
    int tid = threadIdx.x;
    int base = blockIdx.x * 4;
    for (int r = 0; r < 4; r++) {
        int i = base + r;
        float a[4];
#pragma unroll
        for (int c = 0; c < 4; c++) a[c] = __fdiv_rn(yb[i * 4 + c], IMG);
        int lab = yl[i];
        for (int j = tid; j < N2; j += 256) {
            if (fl[j] == lab) {
                float bb[4] = {b2n[j * 4], b2n[j * 4 + 1], b2n[j * 4 + 2], b2n[j * 4 + 3]};
                float v = iou_f(a, bb);
                if (v >= MATCH_IOU_T) {
                    int pos = atomicAdd(mpcount, 1);
                    if (pos < MCAP) { mpk[pos] = (((u64)(u32)i) << 32) | (u32)j; mpi[pos] = v; }
                }
            }
        }
    }
    if (tid < 4) {
        int i = base + tid;
#pragma unroll
        for (int c = 0; c < 4; c++) mbox[i * 4 + c] = __fdiv_rn(yb[i * 4 + c], IMG);
        mscore[i] = __fmul_rn(ys[i], 0.5f);
    }
}

// K2: exact sequential greedy over the sparse candidate-pair list, then emit
// sort keys for ALL rows (fused former k3). Sort pairs by (i<<32)|j
// (i-ascending groups, j-ascending tie-break == argmax lowest-index
// semantics); thread-0 walk picks per-i the strict-max unused iou (always
// >= 0.8 by construction => merge); parallel apply; keys phase.
__global__ void __launch_bounds__(256) k2_match(const float* b2n, const float* s2w,
                                                const int* mpcount, const u64* mpk,
                                                const float* mpi, float* mbox,
                                                float* mscore, int* valid2, u64* keys) {
    __shared__ u64 pk[MCAP];            // 32 KB
    __shared__ float pv[MCAP];          // 16 KB
    __shared__ unsigned char dec[MCAP]; //  4 KB
    __shared__ unsigned char used[N2];  //  2 KB
    int tid = threadIdx.x;
    int np = *mpcount;
    if (np > MCAP) np = MCAP;
    for (int t = tid; t < MCAP; t += 256) {
        pk[t] = (t < np) ? mpk[t] : ~0ULL;
        pv[t] = (t < np) ? mpi[t] : 0.0f;
        dec[t] = 0;
    }
    for (int j = tid; j < N2; j += 256) used[j] = 0;
    __syncthreads();
    if (np > 0) {
        // runtime-sized bitonic sort of (pk, pv) by pk
        int m = 2;
        while (m < np) m <<= 1;
        for (int k2 = 2; k2 <= m; k2 <<= 1) {
            for (int jj = k2 >> 1; jj > 0; jj >>= 1) {
                for (int idx = tid; idx < m; idx += 256) {
                    int l = idx ^ jj;
                    if (l > idx) {
                        u64 A = pk[idx], B = pk[l];
                        bool up = ((idx & k2) == 0);
                        if (up ? (A > B) : (A < B)) {
                            pk[idx] = B; pk[l] = A;
                            float fA = pv[idx]; pv[idx] = pv[l]; pv[l] = fA;
                        }
                    }
                }
                __syncthreads();
            }
        }
        // serial greedy walk (np ~ hundreds)
        if (tid == 0) {
            int cur_i = -1, best_p = -1, best_j = -1;
            float best_v = -1.0f;
            for (int p = 0; p < np; p++) {
                u64 pr = pk[p];
                int i = (int)(pr >> 32);
                int j = (int)(pr & 0xffffffffu);
                if (i != cur_i) {
                    if (best_p >= 0) { dec[best_p] = 1; used[best_j] = 1; }
                    cur_i = i; best_p = -1; best_j = -1; best_v = -1.0f;
                }
                if (!used[j]) {
                    float v = pv[p];
                    if (v > best_v) { best_v = v; best_p = p; best_j = j; }
                }
            }
            if (best_p >= 0) { dec[best_p] = 1; used[best_j] = 1; }
        }
        __syncthreads();
        // parallel apply (at most one dec'd pair per i -> disjoint writes)
        for (int p = tid; p < np; p += 256) {
            if (dec[p]) {
                u64 pr = pk[p];
                int i = (int)(pr >> 32);
                int j = (int)(pr & 0xffffffffu);
                float s2 = s2w[j];
                float sc0 = mscore[i];
                float tot = __fadd_rn(sc0, s2);
#pragma unroll
                for (int cc = 0; cc < 4; cc++) {
                    float merged = __fdiv_rn(
                        __fadd_rn(__fmul_rn(mbox[i * 4 + cc], sc0),
                                  __fmul_rn(b2n[j * 4 + cc], s2)), tot);
                    mbox[i * 4 + cc] = merged;
                }
                mscore[i] = tot;
            }
        }
        __syncthreads();   // apply's global writes visible block-wide
    }
    // keys phase (fused k3): stable argsort(-where(valid,s,-1)) == ascending
    // sort of ((~sortable_f32(val)) << 32) | index.
    for (int idx = tid; idx < NT; idx += 256) {
        float sc; int val;
        if (idx < N1) { sc = mscore[idx]; val = 1; }
        else          { sc = s2w[idx - N1]; val = used[idx - N1] ? 0 : 1; }
        float f = val ? sc : -1.0f;
        u32 u = __float_as_uint(f);
        u32 asc = (u >> 31) ? ~u : (u | 0x80000000u);
        keys[idx] = (((u64)(~asc)) << 32) | (u32)idx;
    }
    for (int j = tid; j < N2; j += 256) valid2[j] = used[j] ? 0 : 1;
}

// K4: rank-count + direct scatter-gather (fused former k5). 384 blocks x 16
// source rows; keys read straight from L2 (each cached line hit 384x); rank
// r is unique (composite keys unique), so scatter writes are disjoint.
__global__ void __launch_bounds__(256) k4_rank(const u64* keys, const float* mbox,
                                               const float* mscore, const float* b2n,
                                               const float* s2w, const int* valid2,
                                               const int* yl, const int* fl,
                                               float* sboxn, int* slab, int* svalid,
                                               float* out) {
    __shared__ int cnts[16];
    int tid = threadIdx.x;
    if (tid < 16) cnts[tid] = 0;
    int i0 = blockIdx.x * 16;
    u64 myk[16];
#pragma unroll
    for (int g = 0; g < 16; g++) myk[g] = keys[i0 + g];
    int local[16];
#pragma unroll
    for (int g = 0; g < 16; g++) local[g] = 0;
    __syncthreads();
    for (int j = tid; j < NT; j += 256) {
        u64 kj = keys[j];
#pragma unroll
        for (int g = 0; g < 16; g++) local[g] += (kj < myk[g]) ? 1 : 0;
    }
#pragma unroll
    for (int g = 0; g < 16; g++) {
        int v = local[g];
#pragma unroll
        for (int s = 32; s > 0; s >>= 1) v += __shfl_down(v, s, 64);
        if ((tid & 63) == 0) atomicAdd(&cnts[g], v);
    }
    __syncthreads();
    if (tid < 16) {
        int i = i0 + tid;
        int r = cnts[tid];
        float b[4]; int lab; float sc; int val;
        if (i < N1) {
#pragma unroll
            for (int c = 0; c < 4; c++) b[c] = mbox[i * 4 + c];
            lab = yl[i]; sc = mscore[i]; val = 1;
        } else {
            int j = i - N1;
#pragma unroll
            for (int c = 0; c < 4; c++) b[c] = b2n[j * 4 + c];
            lab = fl[j]; sc = s2w[j]; val = valid2[j];
        }
#pragma unroll
        for (int c = 0; c < 4; c++) {
            sboxn[r * 4 + c] = b[c];
            out[r * 4 + c] = __fmul_rn(b[c], IMG);
        }
        slab[r] = lab; svalid[r] = val;
        out[24576 + r] = (lab == 0) ? 2.0f : 1.0f;   // label_map[clip(l,0,1)]
        out[24576 + NT + r] = sc;                     // sorted scores
    }
}

// K6: NMS candidate pairs (i<j, same label, IoU >= 0.95), 4 rows per block.
__global__ void __launch_bounds__(256) k6_pairs(const float* sboxn, const int* slab,
                                                int* pcount, u64* pairs) {
    int tid = threadIdx.x;
    int base = blockIdx.x * 4;
    for (int r = 0; r < 4; r++) {
        int i = base + r;
        float a[4] = {sboxn[i * 4], sboxn[i * 4 + 1], sboxn[i * 4 + 2], sboxn[i * 4 + 3]};
        int lab = slab[i];
        for (int j = i + 1 + tid; j < NT; j += 256) {
            if (slab[j] == lab) {
                float bb[4] = {sboxn[j * 4], sboxn[j * 4 + 1], sboxn[j * 4 + 2], sboxn[j * 4 + 3]};
                if (iou_f(a, bb) >= NMS_IOU_T) {
                    int pos = atomicAdd(pcount, 1);
                    if (pos < CAP) pairs[pos] = (((u64)(u32)i) << 32) | (u32)j;
                }
            }
        }
    }
}

// K7: sort pairs (restores determinism after atomic append), then exact
// sequential suppression resolution; write keep mask. Runtime-sized bitonic.
__global__ void __launch_bounds__(256) k7_resolve(const int* pcount, const u64* pairs,
                                                  const int* svalid, float* out) {
    __shared__ u64 pl[CAP];
    __shared__ unsigned char sup[NT];
    int tid = threadIdx.x;
    int np = *pcount;
    if (np > CAP) np = CAP;
    int m = 2;
    while (m < np) m <<= 1;   // block-uniform
    for (int t = tid; t < m; t += 256) pl[t] = (t < np) ? pairs[t] : ~0ULL;
    for (int k = tid; k < NT; k += 256) sup[k] = svalid[k] ? 0 : 1;
    __syncthreads();
    if (np > 0) {
        for (int k2 = 2; k2 <= m; k2 <<= 1) {
            for (int jj = k2 >> 1; jj > 0; jj >>= 1) {
                for (int idx = tid; idx < m; idx += 256) {
                    int l = idx ^ jj;
                    if (l > idx) {
                        u64 A = pl[idx], B = pl[l];
                        bool up = ((idx & k2) == 0);
                        if (up ? (A > B) : (A < B)) { pl[idx] = B; pl[l] = A; }
                    }
                }
                __syncthreads();
            }
        }
        if (tid == 0) {
            for (int p = 0; p < np; p++) {
                u64 pr = pl[p];
                int i = (int)(pr >> 32);
                int j = (int)(pr & 0xffffffffu);
                if (!sup[i]) sup[j] = 1;
            }
        }
        __syncthreads();
    }
    for (int k = tid; k < NT; k += 256) out[24576 + 2 * NT + k] = sup[k] ? 0.0f : 1.0f;
}

extern "C" void kernel_launch(void* const* d_in, const int* in_sizes, int n_in,
                              void* d_out, int out_size, void* d_ws, size_t ws_size,
                              hipStream_t stream) {
    const float* yb = (const float*)d_in[0];
    const float* ys = (const float*)d_in[1];
    const int*   yl = (const int*)d_in[2];
    const float* fb = (const float*)d_in[3];
    const float* fs = (const float*)d_in[4];
    const int*   fl = (const int*)d_in[5];
    float* out = (float*)d_out;
    char* ws = (char*)d_ws;

    float* b2n     = (float*)(ws);            // 2048*4 f   = 32768 B
    float* s2w     = (float*)(ws + 32768);    // 2048 f     =  8192 B
    float* mbox    = (float*)(ws + 40960);    // 4096*4 f   = 65536 B
    float* mscore  = (float*)(ws + 106496);   // 4096 f     = 16384 B
    int*   valid2  = (int*)  (ws + 122880);   // 2048 i     =  8192 B
    u64*   keys    = (u64*)  (ws + 131072);   // 6144 u64   = 49152 B
    float* sboxn   = (float*)(ws + 180224);   // 6144*4 f   = 98304 B
    int*   slab    = (int*)  (ws + 278528);   // 6144 i     = 24576 B
    int*   svalid  = (int*)  (ws + 303104);   // 6144 i     = 24576 B
    int*   pcount  = (int*)  (ws + 327680);   // 8 B
    int*   mpcount = (int*)  (ws + 327688);   // 8 B
    u64*   mpk     = (u64*)  (ws + 327696);   // 4096 u64   = 32768 B
    float* mpi     = (float*)(ws + 360464);   // 4096 f     = 16384 B
    u64*   pairs   = (u64*)  (ws + 376848);   // 4096 u64   = 32768 B (end ~410 KB)

    hipLaunchKernelGGL(k0_prep,  dim3(32),    dim3(256), 0, stream, fb, fs, b2n, s2w, pcount, mpcount);
    hipLaunchKernelGGL(k1_pairs, dim3(N1/4),  dim3(256), 0, stream, yb, ys, yl, fl, b2n, mbox, mscore, mpcount, mpk, mpi);
    hipLaunchKernelGGL(k2_match, dim3(1),     dim3(256), 0, stream, b2n, s2w, mpcount, mpk, mpi, mbox, mscore, valid2, keys);
    hipLaunchKernelGGL(k4_rank,  dim3(NT/16), dim3(256), 0, stream, keys, mbox, mscore, b2n, s2w, valid2, yl, fl, sboxn, slab, svalid, out);
    hipLaunchKernelGGL(k6_pairs, dim3(NT/4),  dim3(256), 0, stream, sboxn, slab, pcount, pairs);
    hipLaunchKernelGGL(k7_resolve,dim3(1),    dim3(256), 0, stream, pcount, pairs, svalid, out);
}